// Round 6
// baseline (86.502 us; speedup 1.0000x reference)
//
#include <hip/hip_runtime.h>

typedef _Float16 f16x8 __attribute__((ext_vector_type(8)));
typedef float floatx4 __attribute__((ext_vector_type(4)));

#define NPTS   10240          // 1024*10 evaluation points
#define GRID   2112           // g(t) grid points = 22 * 96
#define GM1    2111.0f
#define NBLK_MLP 22

// ws byte offsets
#define WS_STEPS 0        // 33 f32
#define WS_CCW   256      // 33 f32
#define WS_MINX  512      // 1 f32 (raw-bits atomicMax slot; poison 0xAAAAAAAA is safe init)
#define WS_X     1024     // 10240 f32
#define WS_W2IMG 65536    // 131072 B: f16 W2 as 4 quadrant LDS images (linear-copyable)
#define WS_G     196608   // GRID f32 g(t) grid values

__device__ __forceinline__ float elu1(float v) {
  return v > 0.f ? v : __expf(v) - 1.f;
}

// async global->LDS, 16B per lane; LDS dest = wave-uniform base + lane*16
__device__ __forceinline__ void gload_lds16(const void* g, void* l) {
  __builtin_amdgcn_global_load_lds(
      (const __attribute__((address_space(1))) unsigned int*)g,
      (__attribute__((address_space(3))) unsigned int*)l,
      16, 0, 0);
}

// ---------------------------------------------------------------------------
// pre: blocks 0..31 -> W2 quadrant images; 32 -> CC consts;
//      33..36 -> log-softmax (256 rows each) + block-min -> atomicMax(bits)
// (for negative floats, float-min == unsigned-max of raw bits; all x <= ~-1,
//  bits >= 0xBF800000 > poison 0xAAAAAAAA, so the poisoned slot needs no init)
// ---------------------------------------------------------------------------
__global__ void k_pre(const float* __restrict__ logits,
                      const float* __restrict__ W2,
                      unsigned char* __restrict__ ws)
{
  __shared__ float red[256];
  const int bid = blockIdx.x, tid = threadIdx.x;
  if (bid < 32) {
    int u    = (bid << 8) + tid;         // 0..8191 16B-units
    int col  = u & 127;                  // fastest -> coalesced W2 reads
    int rest = u >> 7;
    int k16l = rest & 15;
    int q    = rest >> 4;                // 0..3  (= c*2 + kh)
    int c    = q >> 1, kh = q & 1;
    int kbase = kh * 128 + k16l * 8;
    int j     = c * 128 + col;
    union { _Float16 h[8]; uint4 v; } pk;
    #pragma unroll
    for (int i = 0; i < 8; ++i)
      pk.h[i] = (_Float16)W2[(kbase + i) * 256 + j];
    unsigned off = (unsigned)q * 32768u + (unsigned)col * 256u
                 + (unsigned)((k16l ^ (col & 7)) << 4);
    *(uint4*)(ws + WS_W2IMG + off) = pk.v;
  } else if (bid == 32) {
    if (tid <= 32) {
      const double pi = 3.141592653589793238462643383279502884;
      float* steps = (float*)(ws + WS_STEPS);
      float* ccw   = (float*)(ws + WS_CCW);
      steps[tid] = (float)cos((double)tid * pi / 32.0);
      double acc = 0.0;
      for (int i = 0; i <= 32; i += 2) {           // odd i have Wv=0
        double wv = (i == 0) ? 1.0 : 2.0 / (1.0 - (double)(i * i));
        double L  = cos((double)(i * tid) * pi / 32.0);
        if (tid == 0)  L = 0.5;
        if (tid == 32) L *= 0.5;
        acc += L * wv;
      }
      ccw[tid] = (float)(acc * (1.0 / 16.0));      // * 2/nb
    }
  } else {
    // softmax, 1 row per thread (4 blocks x 256 rows)
    int r = ((bid - 33) << 8) + tid;               // 0..1023
    const float* row = logits + r * 10;
    float* x = (float*)(ws + WS_X);
    float v[10]; float m = -3.0e38f;
    #pragma unroll
    for (int c = 0; c < 10; ++c) { v[c] = row[c]; m = fmaxf(m, v[c]); }
    float s = 0.f;
    #pragma unroll
    for (int c = 0; c < 10; ++c) s += __expf(v[c] - m);
    float lse = m + __logf(s);
    float lmin = 3.0e38f;
    #pragma unroll
    for (int c = 0; c < 10; ++c) {
      float z = v[c] - lse;
      x[r * 10 + c] = z;
      lmin = fminf(lmin, z);
    }
    red[tid] = lmin;
    __syncthreads();
    #pragma unroll
    for (int t = 128; t > 0; t >>= 1) {
      if (tid < t) red[tid] = fminf(red[tid], red[tid + t]);
      __syncthreads();
    }
    if (tid == 0)
      atomicMax((unsigned*)(ws + WS_MINX), __float_as_uint(red[0]));
  }
}

// ---------------------------------------------------------------------------
// mlp: evaluate g on the GRID uniform t-grid over [min_x, 0].
// 96 rows/block, 4 waves (2 wm x 2 wn), A(h1) in registers, W2 quadrants
// double-buffered via global_load_lds.
// ---------------------------------------------------------------------------
__global__ __launch_bounds__(256, 2) void k_mlp(
    const unsigned char* __restrict__ ws,
    const float* __restrict__ W1, const float* __restrict__ b1,
    const float* __restrict__ b2, const float* __restrict__ W3,
    const float* __restrict__ b3)
{
  __shared__ unsigned char smem[65536] __attribute__((aligned(16)));
  const int tid  = threadIdx.x;
  const int lane = tid & 63, wid = tid >> 6;
  const int wm = wid >> 1, wn = wid & 1;
  const int l15 = lane & 15, l4 = lane >> 4;

  const unsigned char* img = ws + WS_W2IMG;
  float* g_out = (float*)(const_cast<unsigned char*>(ws) + WS_G);
  const float minx   = __uint_as_float(*(const unsigned*)(ws + WS_MINX));
  const float step_t = minx * (-1.0f / GM1);       // t_r = minx + r*step_t

  const int row_base = blockIdx.x * 96;

  // ---- issue stage(0) (quadrant 0 -> buf0), 8 x 1KB per wave ----
  #pragma unroll
  for (int i = 0; i < 8; ++i) {
    int off = wid * 1024 + i * 4096;
    gload_lds16(img + off + lane * 16, smem + off);
  }

  // ---- preload epilogue constants ----
  float b2r[2][4], w3r[2][4];
  #pragma unroll
  for (int c = 0; c < 2; ++c)
    #pragma unroll
    for (int bj = 0; bj < 4; ++bj) {
      int col = c * 128 + wn * 64 + bj * 16 + l15;
      b2r[c][bj] = b2[col];
      w3r[c][bj] = W3[col];
    }

  // ---- A fragments in registers: A[ai][ks], row=wm*48+ai*16+l15, k=ks*32+l4*8+j
  f16x8 A[3][8];
  {
    float t[3];
    #pragma unroll
    for (int ai = 0; ai < 3; ++ai) {
      int rg = row_base + wm * 48 + ai * 16 + l15;
      t[ai] = fmaf((float)rg, step_t, minx);
    }
    #pragma unroll
    for (int ks = 0; ks < 8; ++ks) {
      int k0 = ks * 32 + l4 * 8;
      float w1v[8], b1v[8];
      *(float4*)&w1v[0] = *(const float4*)(W1 + k0);
      *(float4*)&w1v[4] = *(const float4*)(W1 + k0 + 4);
      *(float4*)&b1v[0] = *(const float4*)(b1 + k0);
      *(float4*)&b1v[4] = *(const float4*)(b1 + k0 + 4);
      #pragma unroll
      for (int ai = 0; ai < 3; ++ai) {
        union { _Float16 h[8]; f16x8 v; } pk;
        #pragma unroll
        for (int j = 0; j < 8; ++j)
          pk.h[j] = (_Float16)elu1(fmaf(t[ai], w1v[j], b1v[j]));
        A[ai][ks] = pk.v;
      }
    }
  }
  __syncthreads();   // drains vmcnt(0): stage(0) landed for all waves

  float pacc[3][4];
  #pragma unroll
  for (int a = 0; a < 3; ++a)
    #pragma unroll
    for (int r = 0; r < 4; ++r) pacc[a][r] = 0.f;

  floatx4 acc[3][4];

  // ---- quadrant pipeline: q = c*2 + kh ----
  #pragma unroll
  for (int q = 0; q < 4; ++q) {
    const int buf = (q & 1) * 32768;
    if (q < 3) {                              // issue next stage -> buf^1
      const int nb = ((q + 1) & 1) * 32768;
      #pragma unroll
      for (int i = 0; i < 8; ++i) {
        int off = wid * 1024 + i * 4096;
        gload_lds16(img + (q + 1) * 32768 + off + lane * 16, smem + nb + off);
      }
    }
    if ((q & 1) == 0) {
      #pragma unroll
      for (int a = 0; a < 3; ++a)
        #pragma unroll
        for (int bj = 0; bj < 4; ++bj) acc[a][bj] = floatx4{0.f, 0.f, 0.f, 0.f};
    }
    const int kh = q & 1;
    #pragma unroll
    for (int kl = 0; kl < 4; ++kl) {
      const int ks = kh * 4 + kl;
      f16x8 bfr[4];
      #pragma unroll
      for (int bj = 0; bj < 4; ++bj) {
        int col  = wn * 64 + bj * 16 + l15;
        int unit = (kl * 4 + l4) ^ (col & 7);
        bfr[bj]  = *(const f16x8*)(smem + buf + col * 256 + (unit << 4));
      }
      #pragma unroll
      for (int ai = 0; ai < 3; ++ai)
        #pragma unroll
        for (int bj = 0; bj < 4; ++bj)
          acc[ai][bj] = __builtin_amdgcn_mfma_f32_16x16x32_f16(
              A[ai][ks], bfr[bj], acc[ai][bj], 0, 0, 0);
    }
    if (q & 1) {                              // epilogue for chunk c = q>>1
      const int c = q >> 1;
      #pragma unroll
      for (int bj = 0; bj < 4; ++bj) {
        float b2v = b2r[c][bj], w3v = w3r[c][bj];
        #pragma unroll
        for (int ai = 0; ai < 3; ++ai)
          #pragma unroll
          for (int rr = 0; rr < 4; ++rr)
            pacc[ai][rr] = fmaf(elu1(acc[ai][bj][rr] + b2v), w3v, pacc[ai][rr]);
      }
    }
    __syncthreads();
  }

  // ---- reduce: within-wave over 16 col-lanes, then across the wn pair ----
  float* part = (float*)smem;            // [wid][48], aliases buf0 (done)
  #pragma unroll
  for (int ai = 0; ai < 3; ++ai)
    #pragma unroll
    for (int rr = 0; rr < 4; ++rr) {
      float v = pacc[ai][rr];
      v += __shfl_xor(v, 1);
      v += __shfl_xor(v, 2);
      v += __shfl_xor(v, 4);
      v += __shfl_xor(v, 8);
      if (l15 == 0) part[wid * 48 + ai * 16 + l4 * 4 + rr] = v;
    }
  __syncthreads();
  if (tid < 96) {
    int wmr = tid / 48, r = tid - wmr * 48;
    float o = part[(wmr * 2) * 48 + r] + part[(wmr * 2 + 1) * 48 + r] + b3[0];
    g_out[row_base + wmr * 48 + r] = elu1(o) + 1.f;
  }
}

// ---------------------------------------------------------------------------
// interp: out[n] = (sum_s ccw[s] * lerp(g_grid, t_ns)) * x[n]*0.5 + offset
// g_grid (8.4KB) staged in LDS; t_ns = x[n]*(steps[s]+1)/2 on the uniform grid.
// ---------------------------------------------------------------------------
__global__ void k_interp(const unsigned char* __restrict__ ws,
                         const float* __restrict__ offset,
                         float* __restrict__ out)
{
  __shared__ float gs[GRID];
  __shared__ float st_l[33], cw_l[33];
  const int tid = threadIdx.x;
  const float* gg = (const float*)(ws + WS_G);
  #pragma unroll
  for (int i = tid; i < GRID; i += 256) gs[i] = gg[i];
  if (tid < 33) {
    st_l[tid] = ((const float*)(ws + WS_STEPS))[tid];
    cw_l[tid] = ((const float*)(ws + WS_CCW))[tid];
  }
  __syncthreads();

  const int n = blockIdx.x * 256 + tid;          // 0..10239
  const float x    = ((const float*)(ws + WS_X))[n];
  const float minx = __uint_as_float(*(const unsigned*)(ws + WS_MINX));
  const float xo   = x / minx;                   // in (0, 1]
  const float a    = xo * (0.5f * GM1);
  const float c0   = GM1 - a;
  float acc = 0.f;
  #pragma unroll 4
  for (int s = 0; s < 33; ++s) {
    float u = fmaf(-a, st_l[s], c0);             // grid coordinate of t_ns
    int i = (int)u;
    i = i > (GRID - 2) ? (GRID - 2) : i;
    i = i < 0 ? 0 : i;
    float f  = u - (float)i;
    float g0 = gs[i], g1 = gs[i + 1];
    acc = fmaf(cw_l[s], fmaf(f, g1 - g0, g0), acc);
  }
  out[n] = fmaf(acc, x * 0.5f, offset[0]);
}

extern "C" void kernel_launch(void* const* d_in, const int* in_sizes, int n_in,
                              void* d_out, int out_size, void* d_ws, size_t ws_size,
                              hipStream_t stream)
{
  const float* logits = (const float*)d_in[0];
  const float* W1     = (const float*)d_in[1];
  const float* b1     = (const float*)d_in[2];
  const float* W2     = (const float*)d_in[3];
  const float* b2     = (const float*)d_in[4];
  const float* W3     = (const float*)d_in[5];
  const float* b3     = (const float*)d_in[6];
  const float* offset = (const float*)d_in[7];
  unsigned char* ws   = (unsigned char*)d_ws;
  float* out          = (float*)d_out;

  k_pre<<<37, 256, 0, stream>>>(logits, W2, ws);
  k_mlp<<<NBLK_MLP, 256, 0, stream>>>(ws, W1, b1, b2, W3, b3);
  k_interp<<<40, 256, 0, stream>>>(ws, offset, out);
}